// Round 1
// baseline (734.024 us; speedup 1.0000x reference)
//
#include <hip/hip_runtime.h>

#define D 64
#define KCODES 1024
#define CHUNK 128
#define LDS_STRIDE 68  // 68*4 = 272 bytes: 16B-aligned rows, breaks 32-bank power-of-2 stride

__global__ void __launch_bounds__(256) vq_en2_kernel(const float* __restrict__ embed,
                                                     float* __restrict__ en2) {
  int k = blockIdx.x * blockDim.x + threadIdx.x;
  if (k >= KCODES) return;
  float s = 0.f;
#pragma unroll
  for (int d = 0; d < D; ++d) {
    float e = embed[d * KCODES + k];
    s = fmaf(e, e, s);
  }
  en2[k] = s;
}

__global__ void __launch_bounds__(256) vq_main_kernel(
    const float* __restrict__ inputs, const float* __restrict__ embed,
    const float* __restrict__ en2, float* __restrict__ out_q,
    float* __restrict__ out_codes, float* __restrict__ out_idx, int N) {
  __shared__ float ldsT[CHUNK * LDS_STRIDE];
  __shared__ float ldsE2[CHUNK];

  int n = blockIdx.x * blockDim.x + threadIdx.x;
  if (n >= N) n = N - 1;  // clamp (duplicate work, identical writes) so all threads hit barriers

  // Load this point's vector into registers (16x float4).
  float f[D];
  {
    const float4* in4 = reinterpret_cast<const float4*>(inputs + (size_t)n * D);
#pragma unroll
    for (int d4 = 0; d4 < D / 4; ++d4) {
      float4 v = in4[d4];
      f[d4 * 4 + 0] = v.x;
      f[d4 * 4 + 1] = v.y;
      f[d4 * 4 + 2] = v.z;
      f[d4 * 4 + 3] = v.w;
    }
  }
  float fn2 = 0.f;
#pragma unroll
  for (int d = 0; d < D; ++d) fn2 = fmaf(f[d], f[d], fn2);

  float best = 3.4e38f;
  int besti = 0;

  for (int kb = 0; kb < KCODES; kb += CHUNK) {
    __syncthreads();
    // Stage CHUNK codes transposed into LDS: ldsT[j][d] = embed[d][kb+j].
    // Global reads coalesced along j; LDS write 8-way conflict is negligible (32 writes/thread).
#pragma unroll
    for (int it = 0; it < (CHUNK * D) / 256; ++it) {
      int i = it * 256 + (int)threadIdx.x;
      int d = i >> 7;           // i / CHUNK
      int j = i & (CHUNK - 1);  // i % CHUNK
      ldsT[j * LDS_STRIDE + d] = embed[d * KCODES + kb + j];
    }
    if (threadIdx.x < CHUNK) ldsE2[threadIdx.x] = en2[kb + threadIdx.x];
    __syncthreads();

#pragma unroll 2
    for (int j = 0; j < CHUNK; ++j) {
      const float* e = &ldsT[j * LDS_STRIDE];
      float a0 = 0.f, a1 = 0.f, a2 = 0.f, a3 = 0.f;  // 4 chains: latency ~64cy < 128cy issue
#pragma unroll
      for (int d = 0; d < D; d += 4) {
        float4 ev = *reinterpret_cast<const float4*>(e + d);  // LDS broadcast, conflict-free
        a0 = fmaf(f[d + 0], ev.x, a0);
        a1 = fmaf(f[d + 1], ev.y, a1);
        a2 = fmaf(f[d + 2], ev.z, a2);
        a3 = fmaf(f[d + 3], ev.w, a3);
      }
      float dot = (a0 + a1) + (a2 + a3);
      // Match reference rounding order: (fn2 - 2*dot) + en2; 2*dot exact, fma rounds once.
      float dist = fmaf(-2.f, dot, fn2) + ldsE2[j];
      if (dist < best) { best = dist; besti = kb + j; }  // strict < => first-occurrence tie-break
    }
  }

  // Epilogue: gather winning code (embed is 256 KB -> L2 resident) and write all 3 outputs.
  float q[D];
#pragma unroll
  for (int d = 0; d < D; ++d) q[d] = embed[d * KCODES + besti];

  float4* oq = reinterpret_cast<float4*>(out_q + (size_t)n * D);
  float4* oc = reinterpret_cast<float4*>(out_codes + (size_t)n * 2 * D);
#pragma unroll
  for (int d4 = 0; d4 < D / 4; ++d4) {
    float4 fv = make_float4(f[4 * d4], f[4 * d4 + 1], f[4 * d4 + 2], f[4 * d4 + 3]);
    float4 qv = make_float4(q[4 * d4], q[4 * d4 + 1], q[4 * d4 + 2], q[4 * d4 + 3]);
    oq[d4] = qv;               // quantized_st forward value == quantized
    oc[d4] = fv;               // codes[..., :64]  = inputs
    oc[D / 4 + d4] = qv;       // codes[..., 64:] = quantized
  }
  out_idx[n] = (float)besti;   // int output stored in the float32 out buffer
}

extern "C" void kernel_launch(void* const* d_in, const int* in_sizes, int n_in,
                              void* d_out, int out_size, void* d_ws, size_t ws_size,
                              hipStream_t stream) {
  const float* inputs = (const float*)d_in[0];
  const float* embed  = (const float*)d_in[1];
  int N = in_sizes[0] / D;  // 32*4096 = 131072

  float* en2 = (float*)d_ws;                     // 1024 floats of scratch
  float* out = (float*)d_out;
  float* out_q     = out;                        // [N, 64]
  float* out_codes = out + (size_t)N * D;        // [N, 128]
  float* out_idx   = out + (size_t)N * D * 3;    // [N]

  vq_en2_kernel<<<(KCODES + 255) / 256, 256, 0, stream>>>(embed, en2);
  vq_main_kernel<<<(N + 255) / 256, 256, 0, stream>>>(inputs, embed, en2,
                                                      out_q, out_codes, out_idx, N);
}

// Round 2
// 574.208 us; speedup vs baseline: 1.2783x; 1.2783x over previous
//
#include <hip/hip_runtime.h>

#define D 64
#define KCODES 1024

// Prep: transpose embed [64][1024] -> embedT [1024][64] (256 B contiguous rows,
// so the main loop's wave-uniform reads become s_load_dwordx4/x16), and compute
// en2[k] = ||e_k||^2 with the SAME sequential-fma order as the R1 kernel
// (numerics must stay bit-identical to the passing version).
__global__ void __launch_bounds__(256) vq_prep_kernel(const float* __restrict__ embed,
                                                      float* __restrict__ embedT,
                                                      float* __restrict__ en2) {
  int k = blockIdx.x * blockDim.x + threadIdx.x;
  if (k >= KCODES) return;
  float s = 0.f;
#pragma unroll
  for (int d = 0; d < D; ++d) {
    float e = embed[d * KCODES + k];  // coalesced along k per d
    embedT[k * D + d] = e;            // scattered writes, 256 KB total: negligible
    s = fmaf(e, e, s);
  }
  en2[k] = s;
}

__global__ void __launch_bounds__(256) vq_main_kernel(
    const float* __restrict__ inputs, const float* __restrict__ embedT,
    const float* __restrict__ en2, float* __restrict__ out_q,
    float* __restrict__ out_codes, float* __restrict__ out_idx, int N) {
  int n = blockIdx.x * blockDim.x + threadIdx.x;
  if (n >= N) n = N - 1;  // clamp: duplicate work, identical writes

  // Point vector in VGPRs (16x float4 loads, coalesced).
  float f[D];
  {
    const float4* in4 = reinterpret_cast<const float4*>(inputs + (size_t)n * D);
#pragma unroll
    for (int d4 = 0; d4 < D / 4; ++d4) {
      float4 v = in4[d4];
      f[4 * d4 + 0] = v.x;
      f[4 * d4 + 1] = v.y;
      f[4 * d4 + 2] = v.z;
      f[4 * d4 + 3] = v.w;
    }
  }
  float fn2 = 0.f;
#pragma unroll
  for (int d = 0; d < D; ++d) fn2 = fmaf(f[d], f[d], fn2);

  float best = 3.4e38f;
  int besti = 0;

  // Hot loop: code k's 64 floats are wave-uniform loads from contiguous 256 B
  // -> scalar s_load through SMEM pipe; fma takes the SGPR operand directly.
  // Zero LDS, zero per-lane VMEM in this loop.
  for (int k = 0; k < KCODES; ++k) {
    const float* __restrict__ e = embedT + (k << 6);
    float a0 = 0.f, a1 = 0.f, a2 = 0.f, a3 = 0.f;  // same 4-chain split as R1
#pragma unroll
    for (int d = 0; d < D; d += 4) {
      a0 = fmaf(f[d + 0], e[d + 0], a0);
      a1 = fmaf(f[d + 1], e[d + 1], a1);
      a2 = fmaf(f[d + 2], e[d + 2], a2);
      a3 = fmaf(f[d + 3], e[d + 3], a3);
    }
    float dot = (a0 + a1) + (a2 + a3);
    float dist = fmaf(-2.f, dot, fn2) + en2[k];  // same rounding order as R1
    if (dist < best) { best = dist; besti = k; }  // strict < = first-occurrence
  }

  // Epilogue: gather winner (divergent, but embedT is 256 KB -> L2-resident).
  const float4* q4 = reinterpret_cast<const float4*>(embedT + ((size_t)besti << 6));
  float4* oq = reinterpret_cast<float4*>(out_q + (size_t)n * D);
  float4* oc = reinterpret_cast<float4*>(out_codes + (size_t)n * 2 * D);
#pragma unroll
  for (int d4 = 0; d4 < D / 4; ++d4) {
    float4 qv = q4[d4];
    float4 fv = make_float4(f[4 * d4], f[4 * d4 + 1], f[4 * d4 + 2], f[4 * d4 + 3]);
    oq[d4] = qv;           // quantized (ST forward value)
    oc[d4] = fv;           // codes[..., :64]  = inputs
    oc[D / 4 + d4] = qv;   // codes[..., 64:] = quantized
  }
  out_idx[n] = (float)besti;
}

extern "C" void kernel_launch(void* const* d_in, const int* in_sizes, int n_in,
                              void* d_out, int out_size, void* d_ws, size_t ws_size,
                              hipStream_t stream) {
  const float* inputs = (const float*)d_in[0];
  const float* embed  = (const float*)d_in[1];
  int N = in_sizes[0] / D;  // 32*4096 = 131072

  float* embedT = (float*)d_ws;            // 1024*64 floats = 256 KB
  float* en2    = embedT + KCODES * D;     // 1024 floats
  float* out = (float*)d_out;
  float* out_q     = out;                     // [N, 64]
  float* out_codes = out + (size_t)N * D;     // [N, 128]
  float* out_idx   = out + (size_t)N * D * 3; // [N]

  vq_prep_kernel<<<(KCODES + 255) / 256, 256, 0, stream>>>(embed, embedT, en2);
  vq_main_kernel<<<(N + 255) / 256, 256, 0, stream>>>(inputs, embedT, en2,
                                                      out_q, out_codes, out_idx, N);
}

// Round 3
// 479.988 us; speedup vs baseline: 1.5293x; 1.1963x over previous
//
#include <hip/hip_runtime.h>

#define D 64
#define KCODES 1024
#define KHALF 512

// Prep: transpose embed [64][1024] -> embedT [1024][64] and en2[k] = ||e_k||^2
// (same fma order as R1/R2 -- numerics must stay identical to passing kernels).
__global__ void __launch_bounds__(256) vq_prep_kernel(const float* __restrict__ embed,
                                                      float* __restrict__ embedT,
                                                      float* __restrict__ en2) {
  int k = blockIdx.x * blockDim.x + threadIdx.x;
  if (k >= KCODES) return;
  float s = 0.f;
#pragma unroll
  for (int d = 0; d < D; ++d) {
    float e = embed[d * KCODES + k];
    embedT[k * D + d] = e;
    s = fmaf(e, e, s);
  }
  en2[k] = s;
}

// Block = 256 threads covering 256 points. Threads 0..127 scan codes [0,512),
// threads 128..255 scan [512,1024), each thread owns 2 points (th, th+128).
// One wave-uniform 256 B scalar row load feeds 2x64 fma -> stall/work halved;
// 2048 total waves (2/SIMD) hide the SMEM lgkmcnt(0) drain.
__global__ void __launch_bounds__(256, 2) vq_main_kernel(
    const float* __restrict__ inputs, const float* __restrict__ embedT,
    const float* __restrict__ en2, float* __restrict__ out_q,
    float* __restrict__ out_codes, float* __restrict__ out_idx) {
  __shared__ float s_best[256];
  __shared__ int   s_idx[256];
  __shared__ int   s_fin[256];

  const int t  = threadIdx.x;
  const int th = t & 127;
  const int base = blockIdx.x * 256;
  const int p0 = base + th;
  const int p1 = base + th + 128;

  // K-half base: wave-uniform in fact; readfirstlane makes it provably so,
  // keeping the row loads on the scalar (s_load) path.
  const int k0 = __builtin_amdgcn_readfirstlane(t >= 128 ? KHALF : 0);
  const float* __restrict__ erow = embedT + ((size_t)k0 << 6);

  // Two point vectors in VGPRs (coalesced float4 loads).
  float f0[D], f1[D];
  {
    const float4* i40 = reinterpret_cast<const float4*>(inputs + (size_t)p0 * D);
    const float4* i41 = reinterpret_cast<const float4*>(inputs + (size_t)p1 * D);
#pragma unroll
    for (int d4 = 0; d4 < D / 4; ++d4) {
      float4 a = i40[d4];
      float4 b = i41[d4];
      f0[4 * d4 + 0] = a.x; f0[4 * d4 + 1] = a.y; f0[4 * d4 + 2] = a.z; f0[4 * d4 + 3] = a.w;
      f1[4 * d4 + 0] = b.x; f1[4 * d4 + 1] = b.y; f1[4 * d4 + 2] = b.z; f1[4 * d4 + 3] = b.w;
    }
  }
  float fn20 = 0.f, fn21 = 0.f;
#pragma unroll
  for (int d = 0; d < D; ++d) fn20 = fmaf(f0[d], f0[d], fn20);
#pragma unroll
  for (int d = 0; d < D; ++d) fn21 = fmaf(f1[d], f1[d], fn21);

  float best0 = 3.4e38f, best1 = 3.4e38f;
  int bi0 = k0, bi1 = k0;

#pragma unroll 1
  for (int kk = 0; kk < KHALF; ++kk) {
    const float* __restrict__ e = erow + (kk << 6);  // uniform -> s_load_dwordx16 x4
    float a0 = 0.f, a1 = 0.f, a2 = 0.f, a3 = 0.f;    // same 4-chain split as R2
    float b0 = 0.f, b1 = 0.f, b2 = 0.f, b3 = 0.f;
#pragma unroll
    for (int d = 0; d < D; d += 4) {
      float e0 = e[d + 0], e1 = e[d + 1], e2 = e[d + 2], e3 = e[d + 3];
      a0 = fmaf(f0[d + 0], e0, a0);
      a1 = fmaf(f0[d + 1], e1, a1);
      a2 = fmaf(f0[d + 2], e2, a2);
      a3 = fmaf(f0[d + 3], e3, a3);
      b0 = fmaf(f1[d + 0], e0, b0);
      b1 = fmaf(f1[d + 1], e1, b1);
      b2 = fmaf(f1[d + 2], e2, b2);
      b3 = fmaf(f1[d + 3], e3, b3);
    }
    float dot0 = (a0 + a1) + (a2 + a3);
    float dot1 = (b0 + b1) + (b2 + b3);
    float en = en2[k0 + kk];                          // uniform -> s_load
    float d0 = fmaf(-2.f, dot0, fn20) + en;           // same rounding order as R2
    float d1 = fmaf(-2.f, dot1, fn21) + en;
    int k = k0 + kk;
    if (d0 < best0) { best0 = d0; bi0 = k; }          // strict < = first occurrence
    if (d1 < best1) { best1 = d1; bi1 = k; }
  }

  // Merge halves: high half publishes its (best, idx); low half combines.
  // Strict < favoring the low half preserves the first-occurrence tie-break.
  if (t >= 128) {
    s_best[th] = best0;       s_idx[th] = bi0;
    s_best[th + 128] = best1; s_idx[th + 128] = bi1;
  }
  __syncthreads();
  if (t < 128) {
    if (s_best[th] < best0) bi0 = s_idx[th];
    if (s_best[th + 128] < best1) bi1 = s_idx[th + 128];
    s_fin[th] = bi0;
    s_fin[th + 128] = bi1;
  }
  __syncthreads();

  // Split epilogue. Winner rows are L2-resident (embedT = 256 KB).
  if (t < 128) {
    // quantized rows + idx for both points
    const float4* q0 = reinterpret_cast<const float4*>(embedT + ((size_t)bi0 << 6));
    const float4* q1 = reinterpret_cast<const float4*>(embedT + ((size_t)bi1 << 6));
    float4* o0 = reinterpret_cast<float4*>(out_q + (size_t)p0 * D);
    float4* o1 = reinterpret_cast<float4*>(out_q + (size_t)p1 * D);
#pragma unroll
    for (int d4 = 0; d4 < D / 4; ++d4) { o0[d4] = q0[d4]; o1[d4] = q1[d4]; }
    out_idx[p0] = (float)bi0;
    out_idx[p1] = (float)bi1;
  } else {
    // codes rows ([inputs | quantized]) for both points
    int fi0 = s_fin[th], fi1 = s_fin[th + 128];
    const float4* q0 = reinterpret_cast<const float4*>(embedT + ((size_t)fi0 << 6));
    const float4* q1 = reinterpret_cast<const float4*>(embedT + ((size_t)fi1 << 6));
    float4* c0 = reinterpret_cast<float4*>(out_codes + (size_t)p0 * 2 * D);
    float4* c1 = reinterpret_cast<float4*>(out_codes + (size_t)p1 * 2 * D);
#pragma unroll
    for (int d4 = 0; d4 < D / 4; ++d4) {
      c0[d4] = make_float4(f0[4 * d4], f0[4 * d4 + 1], f0[4 * d4 + 2], f0[4 * d4 + 3]);
      c1[d4] = make_float4(f1[4 * d4], f1[4 * d4 + 1], f1[4 * d4 + 2], f1[4 * d4 + 3]);
      c0[D / 4 + d4] = q0[d4];
      c1[D / 4 + d4] = q1[d4];
    }
  }
}

extern "C" void kernel_launch(void* const* d_in, const int* in_sizes, int n_in,
                              void* d_out, int out_size, void* d_ws, size_t ws_size,
                              hipStream_t stream) {
  const float* inputs = (const float*)d_in[0];
  const float* embed  = (const float*)d_in[1];
  int N = in_sizes[0] / D;  // 131072

  float* embedT = (float*)d_ws;             // 256 KB
  float* en2    = embedT + KCODES * D;      // 4 KB
  float* out = (float*)d_out;
  float* out_q     = out;                      // [N, 64]
  float* out_codes = out + (size_t)N * D;      // [N, 128]
  float* out_idx   = out + (size_t)N * D * 3;  // [N]

  vq_prep_kernel<<<(KCODES + 255) / 256, 256, 0, stream>>>(embed, embedT, en2);
  vq_main_kernel<<<N / 256, 256, 0, stream>>>(inputs, embedT, en2,
                                              out_q, out_codes, out_idx);
}